// Round 1
// baseline (262.103 us; speedup 1.0000x reference)
//
#include <hip/hip_runtime.h>

// MultiHeadAttention B=16 N=1024 E=768 H=8 D=96 — fp16 MFMA pipeline.
// ws layout (130.6 MB total):
//   WT   [3072][768] fp16 : rows 0-2303 = (Wq|Wk|Wv)^T, rows 2304-3071 = Wo^T
//   bias [2304] f32
//   xh   [16384][768] fp16
//   QKV  [16384][2304] fp16 (cols: 0-767 Q, 768-1535 K, 1536-2303 V; head h at h*96)
//   Oh   [16384][768] fp16 (attention output, pre-projection)

typedef _Float16 half8 __attribute__((ext_vector_type(8)));
typedef float f32x4 __attribute__((ext_vector_type(4)));

__device__ __forceinline__ void gload_lds16(const void* g, void* l) {
  __builtin_amdgcn_global_load_lds((const __attribute__((address_space(1))) void*)g,
                                   (__attribute__((address_space(3))) void*)l, 16, 0, 0);
}

// ---------------- converts ----------------

__global__ __launch_bounds__(256) void conv_x_kernel(const float* __restrict__ x,
                                                     _Float16* __restrict__ xh) {
  long i = ((long)blockIdx.x * 256 + threadIdx.x) * 8;
  float4 a = *(const float4*)(x + i);
  float4 b = *(const float4*)(x + i + 4);
  half8 o;
  o[0] = (_Float16)a.x; o[1] = (_Float16)a.y; o[2] = (_Float16)a.z; o[3] = (_Float16)a.w;
  o[4] = (_Float16)b.x; o[5] = (_Float16)b.y; o[6] = (_Float16)b.z; o[7] = (_Float16)b.w;
  *(half8*)(xh + i) = o;
}

__global__ __launch_bounds__(256) void transpose_cvt_kernel(
    const float* __restrict__ W0, const float* __restrict__ W1,
    const float* __restrict__ W2, const float* __restrict__ W3,
    _Float16* __restrict__ WT) {
  __shared__ float tile[32][33];
  int z = blockIdx.z;
  const float* W = (z == 0) ? W0 : (z == 1) ? W1 : (z == 2) ? W2 : W3;
  int k0 = blockIdx.y * 32, n0 = blockIdx.x * 32;
  int tx = threadIdx.x, ty = threadIdx.y;
#pragma unroll
  for (int j = ty; j < 32; j += 8)
    tile[j][tx] = W[(size_t)(k0 + j) * 768 + n0 + tx];
  __syncthreads();
  _Float16* dst = WT + (size_t)z * 768 * 768;
#pragma unroll
  for (int j = ty; j < 32; j += 8)
    dst[(size_t)(n0 + j) * 768 + k0 + tx] = (_Float16)tile[tx][j];
}

__global__ __launch_bounds__(256) void conv_bias_kernel(const float* __restrict__ bq,
                                                        const float* __restrict__ bk,
                                                        const float* __restrict__ bv,
                                                        float* __restrict__ bias) {
  int i = blockIdx.x * 256 + threadIdx.x;
  if (i >= 2304) return;
  bias[i] = (i < 768) ? bq[i] : (i < 1536) ? bk[i - 768] : bv[i - 1536];
}

// ---------------- GEMM: C[M][ldc] = A[M][K] * Bt[N][K]^T + bias ----------------
// m97 structure: 128x128 tile, BK=32, 4 waves (each 64x64 = 4x4 frags of 16x16),
// global_load_lds width=16, 2 barriers per K-step, XCD-swizzled 1D grid.

template <int OUT_F16>
__global__ __launch_bounds__(256) void gemm_nt_kernel(
    const _Float16* __restrict__ A, const _Float16* __restrict__ Bt,
    const float* __restrict__ bias, void* __restrict__ C,
    int M, int N, int K, int ldc) {
  __shared__ _Float16 As[128 * 32];
  __shared__ _Float16 Bs[128 * 32];
  int nbx = N >> 7;
  int nwg = gridDim.x;
  int wg = blockIdx.x;
  int cpx = nwg >> 3;                       // nwg % 8 == 0 guaranteed by launch
  int swz = (wg & 7) * cpx + (wg >> 3);     // XCD-aware bijective swizzle
  int bx = swz % nbx, by = swz / nbx;
  int m0 = by * 128, n0 = bx * 128;
  int t = threadIdx.x, l = t & 63, w = t >> 6;
  int lg = l >> 4, lr = l & 15;
  int wr = w >> 1, wc = w & 1;
  f32x4 acc[4][4] = {};

  for (int k0 = 0; k0 < K; k0 += 32) {
    __syncthreads();  // previous compute done before overwrite
#pragma unroll
    for (int j = 0; j < 2; ++j) {
      int slot = j * 256 + t;
      gload_lds16(A + (size_t)(m0 + (slot >> 2)) * K + k0 + (slot & 3) * 8, &As[slot * 8]);
    }
#pragma unroll
    for (int j = 0; j < 2; ++j) {
      int slot = j * 256 + t;
      gload_lds16(Bt + (size_t)(n0 + (slot >> 2)) * K + k0 + (slot & 3) * 8, &Bs[slot * 8]);
    }
    __syncthreads();  // drains vmcnt -> tiles ready
    half8 af[4], bf[4];
#pragma unroll
    for (int r = 0; r < 4; ++r) af[r] = *(const half8*)&As[(wr * 64 + r * 16 + lr) * 32 + lg * 8];
#pragma unroll
    for (int c = 0; c < 4; ++c) bf[c] = *(const half8*)&Bs[(wc * 64 + c * 16 + lr) * 32 + lg * 8];
#pragma unroll
    for (int r = 0; r < 4; ++r)
#pragma unroll
      for (int c = 0; c < 4; ++c)
        acc[r][c] = __builtin_amdgcn_mfma_f32_16x16x32_f16(af[r], bf[c], acc[r][c], 0, 0, 0);
  }

#pragma unroll
  for (int r = 0; r < 4; ++r)
#pragma unroll
    for (int c = 0; c < 4; ++c) {
      int col = n0 + wc * 64 + c * 16 + lr;
      float bb = bias[col];
#pragma unroll
      for (int i = 0; i < 4; ++i) {
        int row = m0 + wr * 64 + r * 16 + lg * 4 + i;  // D: col=lane&15, row=4*(lane>>4)+i
        float v = acc[r][c][i] + bb;
        if (OUT_F16)
          ((_Float16*)C)[(size_t)row * ldc + col] = (_Float16)v;
        else
          ((float*)C)[(size_t)row * ldc + col] = v;
      }
    }
}

// ---------------- flash attention ----------------
// grid (128, 16): x = b*8+h, y = q-tile of 64. 4 waves; wave w owns q rows w*16..w*16+15.
// Swapped QK^T: S^T = mfma(K_frag, Q_frag) so kv is (reg,group)-local, q = lane&15.
// softmax(energy) with NO pre-scale; final O /= (l_run * sqrt(768)).

__global__ __launch_bounds__(256) void attn_kernel(const _Float16* __restrict__ QKV,
                                                   _Float16* __restrict__ Oh) {
  constexpr float LOG2E = 1.4426950408889634f;
  int bh = blockIdx.x, qt = blockIdx.y;
  int b = bh >> 3, h = bh & 7;
  int t = threadIdx.x, w = t >> 6, l = t & 63;
  int lg = l >> 4, lr = l & 15;

  __shared__ _Float16 Ks[64 * 128];     // [kv][16 segs of 8] seg XOR-swizzled by kv&7
  __shared__ _Float16 Vts[96 * 64];     // [d][kv], kv XOR-swizzled by ((d^(d>>3))&7)<<3
  __shared__ _Float16 Ps[4][16 * 64];   // per-wave [q][kv], kv XOR-swizzled by (q&7)<<3

  const _Float16* Qb = QKV + (size_t)b * 1024 * 2304 + h * 96;
  const _Float16* Kb = Qb + 768;
  const _Float16* Vb = Qb + 1536;

  half8 qf[3];
  {
    int qrow = qt * 64 + w * 16 + lr;
#pragma unroll
    for (int c = 0; c < 3; ++c)
      qf[c] = *(const half8*)&Qb[(size_t)qrow * 2304 + c * 32 + lg * 8];
  }

  float m_run = -3.0e38f, l_run = 0.f;
  f32x4 o_acc[6] = {};  // O[q=4g+i][d=cc*16+lr]

  for (int kv0 = 0; kv0 < 1024; kv0 += 64) {
    __syncthreads();  // protect LDS from overwrite while prior tile still in use
    // --- stage K: 64 rows x 16 segs of 16B (segs 12-15 harmless overfetch into next cols).
    // LDS dest linear (global_load_lds requirement); source seg pre-swizzled (m173).
#pragma unroll
    for (int j = 0; j < 4; ++j) {
      int slot = j * 256 + t;
      int kv = slot >> 4, seg = slot & 15;
      int segr = seg ^ (kv & 7);
      gload_lds16(Kb + (size_t)(kv0 + kv) * 2304 + segr * 8, &Ks[slot * 8]);
    }
    // --- stage V transposed: unit u -> kv pair 2*(u/12), d-run 8*(u%12)
#pragma unroll
    for (int uu = 0; uu < 2; ++uu) {
      int u = uu * 256 + t;
      if (u < 384) {
        int kvp = u / 12, m = u % 12;
        half8 v0 = *(const half8*)&Vb[(size_t)(kv0 + 2 * kvp) * 2304 + m * 8];
        half8 v1 = *(const half8*)&Vb[(size_t)(kv0 + 2 * kvp + 1) * 2304 + m * 8];
#pragma unroll
        for (int e = 0; e < 8; ++e) {
          int d = m * 8 + e;
          int sw = ((d & 7) ^ ((d >> 3) & 7)) << 3;
          union { _Float16 h2[2]; unsigned u32; } pk;
          pk.h2[0] = v0[e]; pk.h2[1] = v1[e];
          *(unsigned*)&Vts[d * 64 + ((2 * kvp) ^ sw)] = pk.u32;
        }
      }
    }
    __syncthreads();  // drains vmcnt+lgkmcnt -> K,V ready

    // --- S^T tiles: mfma(A=K[16kv][32d], B=Q^T) -> D[kv=4g+i][q=lr]
    f32x4 s_acc[4];
#pragma unroll
    for (int tt = 0; tt < 4; ++tt) {
      s_acc[tt] = f32x4{0.f, 0.f, 0.f, 0.f};
      int kvr = tt * 16 + lr;
#pragma unroll
      for (int c = 0; c < 3; ++c) {
        half8 kf = *(const half8*)&Ks[kvr * 128 + ((c * 4 + lg) ^ (kvr & 7)) * 8];
        s_acc[tt] = __builtin_amdgcn_mfma_f32_16x16x32_f16(kf, qf[c], s_acc[tt], 0, 0, 0);
      }
    }

    // --- online softmax; lane owns q = lr; kv values at tt*16 + 4*lg + i
    float tmax = -3.0e38f;
#pragma unroll
    for (int tt = 0; tt < 4; ++tt)
#pragma unroll
      for (int i = 0; i < 4; ++i) tmax = fmaxf(tmax, s_acc[tt][i]);
    tmax = fmaxf(tmax, __shfl_xor(tmax, 16, 64));
    tmax = fmaxf(tmax, __shfl_xor(tmax, 32, 64));
    float m_new = fmaxf(m_run, tmax);
    float scale = __builtin_exp2f((m_run - m_new) * LOG2E);
    float rs = 0.f;
    _Float16 ph[4][4];
#pragma unroll
    for (int tt = 0; tt < 4; ++tt)
#pragma unroll
      for (int i = 0; i < 4; ++i) {
        float p = __builtin_exp2f((s_acc[tt][i] - m_new) * LOG2E);
        rs += p;
        ph[tt][i] = (_Float16)p;
      }
    rs += __shfl_xor(rs, 16, 64);
    rs += __shfl_xor(rs, 32, 64);
    l_run = l_run * scale + rs;
    m_run = m_new;

    // --- write P (as [q][kv], swizzled) — wave-private buffer, no barrier needed
    {
      int swq = (lr & 7) << 3;
#pragma unroll
      for (int tt = 0; tt < 4; ++tt)
#pragma unroll
        for (int ip = 0; ip < 2; ++ip) {
          int kvb = tt * 16 + lg * 4 + ip * 2;
          union { _Float16 h2[2]; unsigned u32; } pk;
          pk.h2[0] = ph[tt][ip * 2]; pk.h2[1] = ph[tt][ip * 2 + 1];
          *(unsigned*)&Ps[w][lr * 64 + (kvb ^ swq)] = pk.u32;
        }
    }

    // --- rescale O (O rows are q=4*lg+i; scale lives on lane q) ---
    float sc0 = __shfl(scale, lg * 4 + 0, 64);
    float sc1 = __shfl(scale, lg * 4 + 1, 64);
    float sc2 = __shfl(scale, lg * 4 + 2, 64);
    float sc3 = __shfl(scale, lg * 4 + 3, 64);
#pragma unroll
    for (int cc = 0; cc < 6; ++cc) {
      o_acc[cc][0] *= sc0; o_acc[cc][1] *= sc1;
      o_acc[cc][2] *= sc2; o_acc[cc][3] *= sc3;
    }

    // --- PV: O += P[16q][32kv] * V[32kv][16d] per (kc, cc)
#pragma unroll
    for (int kc = 0; kc < 2; ++kc) {
      half8 pf = *(const half8*)&Ps[w][lr * 64 + ((kc * 32 + lg * 8) ^ ((lr & 7) << 3))];
#pragma unroll
      for (int cc = 0; cc < 6; ++cc) {
        int d = cc * 16 + lr;
        int sw = ((d & 7) ^ ((d >> 3) & 7)) << 3;
        half8 vf = *(const half8*)&Vts[d * 64 + ((kc * 32 + lg * 8) ^ sw)];
        o_acc[cc] = __builtin_amdgcn_mfma_f32_16x16x32_f16(pf, vf, o_acc[cc], 0, 0, 0);
      }
    }
  }

  // --- epilogue: O /= (l_run * sqrt(768)) — the reference's post-softmax scaling
  float inv = 1.0f / (l_run * 27.712812921102035f);
  float iv0 = __shfl(inv, lg * 4 + 0, 64);
  float iv1 = __shfl(inv, lg * 4 + 1, 64);
  float iv2 = __shfl(inv, lg * 4 + 2, 64);
  float iv3 = __shfl(inv, lg * 4 + 3, 64);
  size_t rbase = (size_t)(b * 1024 + qt * 64 + w * 16) * 768 + h * 96;
#pragma unroll
  for (int cc = 0; cc < 6; ++cc) {
    int col = cc * 16 + lr;
    Oh[rbase + (size_t)(lg * 4 + 0) * 768 + col] = (_Float16)(o_acc[cc][0] * iv0);
    Oh[rbase + (size_t)(lg * 4 + 1) * 768 + col] = (_Float16)(o_acc[cc][1] * iv1);
    Oh[rbase + (size_t)(lg * 4 + 2) * 768 + col] = (_Float16)(o_acc[cc][2] * iv2);
    Oh[rbase + (size_t)(lg * 4 + 3) * 768 + col] = (_Float16)(o_acc[cc][3] * iv3);
  }
}

// ---------------- launch ----------------

extern "C" void kernel_launch(void* const* d_in, const int* in_sizes, int n_in,
                              void* d_out, int out_size, void* d_ws, size_t ws_size,
                              hipStream_t stream) {
  const float* x  = (const float*)d_in[0];
  const float* Wq = (const float*)d_in[1];
  const float* bq = (const float*)d_in[2];
  const float* Wk = (const float*)d_in[3];
  const float* bk = (const float*)d_in[4];
  const float* Wv = (const float*)d_in[5];
  const float* bv = (const float*)d_in[6];
  const float* Wo = (const float*)d_in[7];
  const float* bo = (const float*)d_in[8];
  float* out = (float*)d_out;

  char* ws = (char*)d_ws;
  _Float16* WT   = (_Float16*)(ws);                // 4,718,592 B
  float*    bias = (float*)(ws + 4718592);         // 9,216 B (padded to 32K)
  _Float16* xh   = (_Float16*)(ws + 4751360);      // 25,165,824 B
  _Float16* QKV  = (_Float16*)(ws + 29917184);     // 75,497,472 B
  _Float16* Oh   = (_Float16*)(ws + 105414656);    // 25,165,824 B  (total ~130.6 MB)

  conv_x_kernel<<<6144, 256, 0, stream>>>(x, xh);
  transpose_cvt_kernel<<<dim3(24, 24, 4), dim3(32, 8), 0, stream>>>(Wq, Wk, Wv, Wo, WT);
  conv_bias_kernel<<<9, 256, 0, stream>>>(bq, bk, bv, bias);

  // QKV: M=16384, N=2304, K=768 -> grid 128*18 = 2304 (div by 8 for XCD swizzle)
  gemm_nt_kernel<1><<<2304, 256, 0, stream>>>(xh, WT, bias, QKV, 16384, 2304, 768, 2304);

  attn_kernel<<<dim3(128, 16), 256, 0, stream>>>(QKV, Oh);

  // out-proj: M=16384, N=768, K=768 -> grid 128*6 = 768
  gemm_nt_kernel<0><<<768, 256, 0, stream>>>(Oh, WT + (size_t)2304 * 768, bo, out,
                                             16384, 768, 768, 768);
}

// Round 2
// 240.701 us; speedup vs baseline: 1.0889x; 1.0889x over previous
//
#include <hip/hip_runtime.h>

// MultiHeadAttention B=16 N=1024 E=768 H=8 D=96 — fp16 MFMA pipeline.
// ws layout (130.6 MB total):
//   WT   [3072][768] fp16 : rows 0-2303 = (Wq|Wk|Wv)^T, rows 2304-3071 = Wo^T
//   bias [2304] f32
//   xh   [16384][768] fp16
//   QKV  [16384][2304] fp16 (cols: 0-767 Q, 768-1535 K, 1536-2303 V; head h at h*96)
//   Oh   [16384][768] fp16 (attention output, pre-projection)

typedef _Float16 half8 __attribute__((ext_vector_type(8)));
typedef float f32x4 __attribute__((ext_vector_type(4)));

__device__ __forceinline__ void gload_lds16(const void* g, void* l) {
  __builtin_amdgcn_global_load_lds((const __attribute__((address_space(1))) void*)g,
                                   (__attribute__((address_space(3))) void*)l, 16, 0, 0);
}

// ---------------- converts ----------------

__global__ __launch_bounds__(256) void conv_x_kernel(const float* __restrict__ x,
                                                     _Float16* __restrict__ xh) {
  long i = ((long)blockIdx.x * 256 + threadIdx.x) * 8;
  float4 a = *(const float4*)(x + i);
  float4 b = *(const float4*)(x + i + 4);
  half8 o;
  o[0] = (_Float16)a.x; o[1] = (_Float16)a.y; o[2] = (_Float16)a.z; o[3] = (_Float16)a.w;
  o[4] = (_Float16)b.x; o[5] = (_Float16)b.y; o[6] = (_Float16)b.z; o[7] = (_Float16)b.w;
  *(half8*)(xh + i) = o;
}

__global__ __launch_bounds__(256) void transpose_cvt_kernel(
    const float* __restrict__ W0, const float* __restrict__ W1,
    const float* __restrict__ W2, const float* __restrict__ W3,
    _Float16* __restrict__ WT) {
  __shared__ float tile[32][33];
  int z = blockIdx.z;
  const float* W = (z == 0) ? W0 : (z == 1) ? W1 : (z == 2) ? W2 : W3;
  int k0 = blockIdx.y * 32, n0 = blockIdx.x * 32;
  int tx = threadIdx.x, ty = threadIdx.y;
#pragma unroll
  for (int j = ty; j < 32; j += 8)
    tile[j][tx] = W[(size_t)(k0 + j) * 768 + n0 + tx];
  __syncthreads();
  _Float16* dst = WT + (size_t)z * 768 * 768;
#pragma unroll
  for (int j = ty; j < 32; j += 8)
    dst[(size_t)(n0 + j) * 768 + k0 + tx] = (_Float16)tile[tx][j];
}

__global__ __launch_bounds__(256) void conv_bias_kernel(const float* __restrict__ bq,
                                                        const float* __restrict__ bk,
                                                        const float* __restrict__ bv,
                                                        float* __restrict__ bias) {
  int i = blockIdx.x * 256 + threadIdx.x;
  if (i >= 2304) return;
  bias[i] = (i < 768) ? bq[i] : (i < 1536) ? bk[i - 768] : bv[i - 1536];
}

// ---------------- GEMM: C[M][ldc] = A[M][K] * Bt[N][K]^T + bias ----------------
// m97 structure: 128x128 tile, BK=32, 4 waves (each 64x64 = 4x4 frags of 16x16),
// global_load_lds width=16, 2 barriers per K-step, XCD-swizzled 1D grid.

template <int OUT_F16>
__global__ __launch_bounds__(256) void gemm_nt_kernel(
    const _Float16* __restrict__ A, const _Float16* __restrict__ Bt,
    const float* __restrict__ bias, void* __restrict__ C,
    int M, int N, int K, int ldc) {
  __shared__ _Float16 As[128 * 32];
  __shared__ _Float16 Bs[128 * 32];
  int nbx = N >> 7;
  int nwg = gridDim.x;
  int wg = blockIdx.x;
  int cpx = nwg >> 3;                       // nwg % 8 == 0 guaranteed by launch
  int swz = (wg & 7) * cpx + (wg >> 3);     // XCD-aware bijective swizzle
  int bx = swz % nbx, by = swz / nbx;
  int m0 = by * 128, n0 = bx * 128;
  int t = threadIdx.x, l = t & 63, w = t >> 6;
  int lg = l >> 4, lr = l & 15;
  int wr = w >> 1, wc = w & 1;
  f32x4 acc[4][4] = {};

  for (int k0 = 0; k0 < K; k0 += 32) {
    __syncthreads();  // previous compute done before overwrite
#pragma unroll
    for (int j = 0; j < 2; ++j) {
      int slot = j * 256 + t;
      gload_lds16(A + (size_t)(m0 + (slot >> 2)) * K + k0 + (slot & 3) * 8, &As[slot * 8]);
    }
#pragma unroll
    for (int j = 0; j < 2; ++j) {
      int slot = j * 256 + t;
      gload_lds16(Bt + (size_t)(n0 + (slot >> 2)) * K + k0 + (slot & 3) * 8, &Bs[slot * 8]);
    }
    __syncthreads();  // drains vmcnt -> tiles ready
    half8 af[4], bf[4];
#pragma unroll
    for (int r = 0; r < 4; ++r) af[r] = *(const half8*)&As[(wr * 64 + r * 16 + lr) * 32 + lg * 8];
#pragma unroll
    for (int c = 0; c < 4; ++c) bf[c] = *(const half8*)&Bs[(wc * 64 + c * 16 + lr) * 32 + lg * 8];
#pragma unroll
    for (int r = 0; r < 4; ++r)
#pragma unroll
      for (int c = 0; c < 4; ++c)
        acc[r][c] = __builtin_amdgcn_mfma_f32_16x16x32_f16(af[r], bf[c], acc[r][c], 0, 0, 0);
  }

#pragma unroll
  for (int r = 0; r < 4; ++r)
#pragma unroll
    for (int c = 0; c < 4; ++c) {
      int col = n0 + wc * 64 + c * 16 + lr;
      float bb = bias[col];
#pragma unroll
      for (int i = 0; i < 4; ++i) {
        int row = m0 + wr * 64 + r * 16 + lg * 4 + i;  // D: col=lane&15, row=4*(lane>>4)+i
        float v = acc[r][c][i] + bb;
        if (OUT_F16)
          ((_Float16*)C)[(size_t)row * ldc + col] = (_Float16)v;
        else
          ((float*)C)[(size_t)row * ldc + col] = v;
      }
    }
}

// ---------------- flash attention ----------------
// 1D grid 1024, 512 threads (8 waves). Logical block: lin = (hw&7)*128 + (hw>>3)
// -> XCD x owns heads 16x..16x+15 (all 8 q-tiles of a head on one XCD's L2).
// QBLK=128 (wave w owns q rows w*16..), KBLK=64, double-buffered K/V staging with
// ONE barrier per tile: sync -> issue stage(t+1, buf^1) -> compute(t, buf).
// Swapped QK^T: S^T = mfma(K_frag, Q_frag); softmax with NO pre-scale;
// final O /= (l_run * sqrt(768)).

__global__ __launch_bounds__(512) void attn_kernel(const _Float16* __restrict__ QKV,
                                                   _Float16* __restrict__ Oh) {
  constexpr float LOG2E = 1.4426950408889634f;
  int hw = blockIdx.x;
  int lin = (hw & 7) * 128 + (hw >> 3);   // XCD-chunked
  int bh = lin >> 3, qt = lin & 7;
  int b = bh >> 3, h = bh & 7;
  int t = threadIdx.x, w = t >> 6, l = t & 63;
  int lg = l >> 4, lr = l & 15;

  __shared__ _Float16 Ks[2][64 * 128];    // [kv][16 segs of 8] seg XOR-swizzled by kv&7
  __shared__ _Float16 Vts[2][96 * 64];    // [d][kv], kv XOR-swizzled by ((d^(d>>3))&7)<<3
  __shared__ _Float16 Ps[8][16 * 64];     // per-wave [q][kv], kv XOR-swizzled by (q&7)<<3

  const _Float16* Qb = QKV + (size_t)b * 1024 * 2304 + h * 96;
  const _Float16* Kb = Qb + 768;
  const _Float16* Vb = Qb + 1536;

  half8 qf[3];
  {
    int qrow = qt * 128 + w * 16 + lr;
#pragma unroll
    for (int c = 0; c < 3; ++c)
      qf[c] = *(const half8*)&Qb[(size_t)qrow * 2304 + c * 32 + lg * 8];
  }

  auto stage = [&](int kv0, int bi) {
    // K: 64 rows x 16 segs of 16B (segs 12-15 harmless overfetch into next cols).
    // LDS dest linear per lane (global_load_lds requirement); source seg pre-swizzled.
#pragma unroll
    for (int j = 0; j < 2; ++j) {
      int slot = j * 512 + t;
      int kv = slot >> 4, seg = slot & 15;
      int segr = seg ^ (kv & 7);
      gload_lds16(Kb + (size_t)(kv0 + kv) * 2304 + segr * 8, &Ks[bi][slot * 8]);
    }
    // V transposed: unit u -> kv pair 2*(u/12), d-run 8*(u%12)
    if (t < 384) {
      int kvp = t / 12, m = t % 12;
      half8 v0 = *(const half8*)&Vb[(size_t)(kv0 + 2 * kvp) * 2304 + m * 8];
      half8 v1 = *(const half8*)&Vb[(size_t)(kv0 + 2 * kvp + 1) * 2304 + m * 8];
#pragma unroll
      for (int e = 0; e < 8; ++e) {
        int d = m * 8 + e;
        int sw = ((d & 7) ^ ((d >> 3) & 7)) << 3;
        union { _Float16 h2[2]; unsigned u32; } pk;
        pk.h2[0] = v0[e]; pk.h2[1] = v1[e];
        *(unsigned*)&Vts[bi][d * 64 + ((2 * kvp) ^ sw)] = pk.u32;
      }
    }
  };

  float m_run = -3.0e38f, l_run = 0.f;
  f32x4 o_acc[6] = {};  // O[q=4g+i][d=cc*16+lr]

  stage(0, 0);

  for (int tile = 0; tile < 16; ++tile) {
    int bi = tile & 1;
    __syncthreads();  // drains vmcnt+lgkmcnt: stage(tile) ready, compute(tile-1) done
    if (tile + 1 < 16) stage((tile + 1) * 64, bi ^ 1);

    // --- S^T tiles: mfma(A=K[16kv][32d], B=Q^T) -> D[kv=4g+i][q=lr]
    f32x4 s_acc[4];
#pragma unroll
    for (int tt = 0; tt < 4; ++tt) {
      s_acc[tt] = f32x4{0.f, 0.f, 0.f, 0.f};
      int kvr = tt * 16 + lr;
#pragma unroll
      for (int c = 0; c < 3; ++c) {
        half8 kf = *(const half8*)&Ks[bi][kvr * 128 + ((c * 4 + lg) ^ (kvr & 7)) * 8];
        s_acc[tt] = __builtin_amdgcn_mfma_f32_16x16x32_f16(kf, qf[c], s_acc[tt], 0, 0, 0);
      }
    }

    // --- online softmax; lane owns q = lr; kv values at tt*16 + 4*lg + i
    float tmax = -3.0e38f;
#pragma unroll
    for (int tt = 0; tt < 4; ++tt)
#pragma unroll
      for (int i = 0; i < 4; ++i) tmax = fmaxf(tmax, s_acc[tt][i]);
    tmax = fmaxf(tmax, __shfl_xor(tmax, 16, 64));
    tmax = fmaxf(tmax, __shfl_xor(tmax, 32, 64));
    float m_new = fmaxf(m_run, tmax);
    float scale = __builtin_exp2f((m_run - m_new) * LOG2E);
    float rs = 0.f;
    _Float16 ph[4][4];
#pragma unroll
    for (int tt = 0; tt < 4; ++tt)
#pragma unroll
      for (int i = 0; i < 4; ++i) {
        float p = __builtin_exp2f((s_acc[tt][i] - m_new) * LOG2E);
        rs += p;
        ph[tt][i] = (_Float16)p;
      }
    rs += __shfl_xor(rs, 16, 64);
    rs += __shfl_xor(rs, 32, 64);
    l_run = l_run * scale + rs;
    m_run = m_new;

    // --- write P (as [q][kv], swizzled) — wave-private buffer, no barrier needed
    {
      int swq = (lr & 7) << 3;
#pragma unroll
      for (int tt = 0; tt < 4; ++tt)
#pragma unroll
        for (int ip = 0; ip < 2; ++ip) {
          int kvb = tt * 16 + lg * 4 + ip * 2;
          union { _Float16 h2[2]; unsigned u32; } pk;
          pk.h2[0] = ph[tt][ip * 2]; pk.h2[1] = ph[tt][ip * 2 + 1];
          *(unsigned*)&Ps[w][lr * 64 + (kvb ^ swq)] = pk.u32;
        }
    }

    // --- rescale O (O rows are q=4*lg+i; scale lives on lane q) ---
    float sc0 = __shfl(scale, lg * 4 + 0, 64);
    float sc1 = __shfl(scale, lg * 4 + 1, 64);
    float sc2 = __shfl(scale, lg * 4 + 2, 64);
    float sc3 = __shfl(scale, lg * 4 + 3, 64);
#pragma unroll
    for (int cc = 0; cc < 6; ++cc) {
      o_acc[cc][0] *= sc0; o_acc[cc][1] *= sc1;
      o_acc[cc][2] *= sc2; o_acc[cc][3] *= sc3;
    }

    // --- PV: O += P[16q][32kv] * V[32kv][16d] per (kc, cc)
#pragma unroll
    for (int kc = 0; kc < 2; ++kc) {
      half8 pf = *(const half8*)&Ps[w][lr * 64 + ((kc * 32 + lg * 8) ^ ((lr & 7) << 3))];
#pragma unroll
      for (int cc = 0; cc < 6; ++cc) {
        int d = cc * 16 + lr;
        int sw = ((d & 7) ^ ((d >> 3) & 7)) << 3;
        half8 vf = *(const half8*)&Vts[bi][d * 64 + ((kc * 32 + lg * 8) ^ sw)];
        o_acc[cc] = __builtin_amdgcn_mfma_f32_16x16x32_f16(pf, vf, o_acc[cc], 0, 0, 0);
      }
    }
  }

  // --- epilogue: O /= (l_run * sqrt(768)) — the reference's post-softmax scaling
  float inv = 1.0f / (l_run * 27.712812921102035f);
  float iv0 = __shfl(inv, lg * 4 + 0, 64);
  float iv1 = __shfl(inv, lg * 4 + 1, 64);
  float iv2 = __shfl(inv, lg * 4 + 2, 64);
  float iv3 = __shfl(inv, lg * 4 + 3, 64);
  size_t rbase = (size_t)(b * 1024 + qt * 128 + w * 16) * 768 + h * 96;
#pragma unroll
  for (int cc = 0; cc < 6; ++cc) {
    int col = cc * 16 + lr;
    Oh[rbase + (size_t)(lg * 4 + 0) * 768 + col] = (_Float16)(o_acc[cc][0] * iv0);
    Oh[rbase + (size_t)(lg * 4 + 1) * 768 + col] = (_Float16)(o_acc[cc][1] * iv1);
    Oh[rbase + (size_t)(lg * 4 + 2) * 768 + col] = (_Float16)(o_acc[cc][2] * iv2);
    Oh[rbase + (size_t)(lg * 4 + 3) * 768 + col] = (_Float16)(o_acc[cc][3] * iv3);
  }
}

// ---------------- launch ----------------

extern "C" void kernel_launch(void* const* d_in, const int* in_sizes, int n_in,
                              void* d_out, int out_size, void* d_ws, size_t ws_size,
                              hipStream_t stream) {
  const float* x  = (const float*)d_in[0];
  const float* Wq = (const float*)d_in[1];
  const float* bq = (const float*)d_in[2];
  const float* Wk = (const float*)d_in[3];
  const float* bk = (const float*)d_in[4];
  const float* Wv = (const float*)d_in[5];
  const float* bv = (const float*)d_in[6];
  const float* Wo = (const float*)d_in[7];
  const float* bo = (const float*)d_in[8];
  float* out = (float*)d_out;

  char* ws = (char*)d_ws;
  _Float16* WT   = (_Float16*)(ws);                // 4,718,592 B
  float*    bias = (float*)(ws + 4718592);         // 9,216 B (padded to 32K)
  _Float16* xh   = (_Float16*)(ws + 4751360);      // 25,165,824 B
  _Float16* QKV  = (_Float16*)(ws + 29917184);     // 75,497,472 B
  _Float16* Oh   = (_Float16*)(ws + 105414656);    // 25,165,824 B  (total ~130.6 MB)

  conv_x_kernel<<<6144, 256, 0, stream>>>(x, xh);
  transpose_cvt_kernel<<<dim3(24, 24, 4), dim3(32, 8), 0, stream>>>(Wq, Wk, Wv, Wo, WT);
  conv_bias_kernel<<<9, 256, 0, stream>>>(bq, bk, bv, bias);

  // QKV: M=16384, N=2304, K=768 -> grid 128*18 = 2304 (div by 8 for XCD swizzle)
  gemm_nt_kernel<1><<<2304, 256, 0, stream>>>(xh, WT, bias, QKV, 16384, 2304, 768, 2304);

  attn_kernel<<<1024, 512, 0, stream>>>(QKV, Oh);

  // out-proj: M=16384, N=768, K=768 -> grid 128*6 = 768
  gemm_nt_kernel<0><<<768, 256, 0, stream>>>(Oh, WT + (size_t)2304 * 768, bo, out,
                                             16384, 768, 768, 768);
}

// Round 4
// 231.835 us; speedup vs baseline: 1.1306x; 1.0382x over previous
//
#include <hip/hip_runtime.h>

// MultiHeadAttention B=16 N=1024 E=768 H=8 D=96 — fp16 MFMA pipeline.
// ws layout (130.6 MB total):
//   WT   [3072][768] fp16 : rows 0-2303 = (Wq|Wk|Wv)^T, rows 2304-3071 = Wo^T
//   bias [2304] f32
//   xh   [16384][768] fp16
//   QKV  [16384][2304] fp16 (cols: 0-767 Q, 768-1535 K, 1536-2303 V; head h at h*96)
//   Oh   [16384][768] fp16 (attention output, pre-projection)

typedef _Float16 half8 __attribute__((ext_vector_type(8)));
typedef __fp16 fp16x2 __attribute__((ext_vector_type(2)));
typedef float f32x4 __attribute__((ext_vector_type(4)));

__device__ __forceinline__ void gload_lds16(const void* g, void* l) {
  __builtin_amdgcn_global_load_lds((const __attribute__((address_space(1))) void*)g,
                                   (__attribute__((address_space(3))) void*)l, 16, 0, 0);
}

// ---------------- converts ----------------

__global__ __launch_bounds__(256) void conv_x_kernel(const float* __restrict__ x,
                                                     _Float16* __restrict__ xh) {
  long i = ((long)blockIdx.x * 256 + threadIdx.x) * 8;
  float4 a = *(const float4*)(x + i);
  float4 b = *(const float4*)(x + i + 4);
  half8 o;
  o[0] = (_Float16)a.x; o[1] = (_Float16)a.y; o[2] = (_Float16)a.z; o[3] = (_Float16)a.w;
  o[4] = (_Float16)b.x; o[5] = (_Float16)b.y; o[6] = (_Float16)b.z; o[7] = (_Float16)b.w;
  *(half8*)(xh + i) = o;
}

__global__ __launch_bounds__(256) void transpose_cvt_kernel(
    const float* __restrict__ W0, const float* __restrict__ W1,
    const float* __restrict__ W2, const float* __restrict__ W3,
    _Float16* __restrict__ WT) {
  __shared__ float tile[32][33];
  int z = blockIdx.z;
  const float* W = (z == 0) ? W0 : (z == 1) ? W1 : (z == 2) ? W2 : W3;
  int k0 = blockIdx.y * 32, n0 = blockIdx.x * 32;
  int tx = threadIdx.x, ty = threadIdx.y;
#pragma unroll
  for (int j = ty; j < 32; j += 8)
    tile[j][tx] = W[(size_t)(k0 + j) * 768 + n0 + tx];
  __syncthreads();
  _Float16* dst = WT + (size_t)z * 768 * 768;
#pragma unroll
  for (int j = ty; j < 32; j += 8)
    dst[(size_t)(n0 + j) * 768 + k0 + tx] = (_Float16)tile[tx][j];
}

__global__ __launch_bounds__(256) void conv_bias_kernel(const float* __restrict__ bq,
                                                        const float* __restrict__ bk,
                                                        const float* __restrict__ bv,
                                                        float* __restrict__ bias) {
  int i = blockIdx.x * 256 + threadIdx.x;
  if (i >= 2304) return;
  bias[i] = (i < 768) ? bq[i] : (i < 1536) ? bk[i - 768] : bv[i - 1536];
}

// ---------------- GEMM: C[M][ldc] = A[M][K] * Bt[N][K]^T + bias ----------------
// m97 structure: 128x128 tile, BK=32, 4 waves (each 64x64 = 4x4 frags of 16x16),
// global_load_lds width=16, 2 barriers per K-step, XCD-swizzled 1D grid.

template <int OUT_F16>
__global__ __launch_bounds__(256) void gemm_nt_kernel(
    const _Float16* __restrict__ A, const _Float16* __restrict__ Bt,
    const float* __restrict__ bias, void* __restrict__ C,
    int M, int N, int K, int ldc) {
  __shared__ _Float16 As[128 * 32];
  __shared__ _Float16 Bs[128 * 32];
  int nbx = N >> 7;
  int nwg = gridDim.x;
  int wg = blockIdx.x;
  int cpx = nwg >> 3;                       // nwg % 8 == 0 guaranteed by launch
  int swz = (wg & 7) * cpx + (wg >> 3);     // XCD-aware bijective swizzle
  int bx = swz % nbx, by = swz / nbx;
  int m0 = by * 128, n0 = bx * 128;
  int t = threadIdx.x, l = t & 63, w = t >> 6;
  int lg = l >> 4, lr = l & 15;
  int wr = w >> 1, wc = w & 1;
  f32x4 acc[4][4] = {};

  for (int k0 = 0; k0 < K; k0 += 32) {
    __syncthreads();  // previous compute done before overwrite
#pragma unroll
    for (int j = 0; j < 2; ++j) {
      int slot = j * 256 + t;
      gload_lds16(A + (size_t)(m0 + (slot >> 2)) * K + k0 + (slot & 3) * 8, &As[slot * 8]);
    }
#pragma unroll
    for (int j = 0; j < 2; ++j) {
      int slot = j * 256 + t;
      gload_lds16(Bt + (size_t)(n0 + (slot >> 2)) * K + k0 + (slot & 3) * 8, &Bs[slot * 8]);
    }
    __syncthreads();  // drains vmcnt -> tiles ready
    half8 af[4], bf[4];
#pragma unroll
    for (int r = 0; r < 4; ++r) af[r] = *(const half8*)&As[(wr * 64 + r * 16 + lr) * 32 + lg * 8];
#pragma unroll
    for (int c = 0; c < 4; ++c) bf[c] = *(const half8*)&Bs[(wc * 64 + c * 16 + lr) * 32 + lg * 8];
#pragma unroll
    for (int r = 0; r < 4; ++r)
#pragma unroll
      for (int c = 0; c < 4; ++c)
        acc[r][c] = __builtin_amdgcn_mfma_f32_16x16x32_f16(af[r], bf[c], acc[r][c], 0, 0, 0);
  }

#pragma unroll
  for (int r = 0; r < 4; ++r)
#pragma unroll
    for (int c = 0; c < 4; ++c) {
      int col = n0 + wc * 64 + c * 16 + lr;
      float bb = bias[col];
#pragma unroll
      for (int i = 0; i < 4; ++i) {
        int row = m0 + wr * 64 + r * 16 + lg * 4 + i;  // D: col=lane&15, row=4*(lane>>4)+i
        float v = acc[r][c][i] + bb;
        if (OUT_F16)
          ((_Float16*)C)[(size_t)row * ldc + col] = (_Float16)v;
        else
          ((float*)C)[(size_t)row * ldc + col] = v;
      }
    }
}

// ---------------- flash attention ----------------
// 1D grid 1024, 512 threads (8 waves). Logical block: lin = (hw&7)*128 + (hw>>3)
// -> XCD x owns heads 16x..16x+15 (all 8 q-tiles of a head on one XCD's L2).
// QBLK=128 (wave w owns q rows w*16..), KBLK=64, double-buffered K/V staging,
// ONE barrier per tile. Swapped QK^T (S^T = mfma(K,Q)); Q pre-scaled by LOG2E so
// exp2 args need no multiply; defer-max (THR=11.5 log2-units) skips O-rescale on
// most tiles; P packed via v_cvt_pkrtz + b64 writes. O /= (l_run * sqrt(768)).

__global__ __launch_bounds__(512) void attn_kernel(const _Float16* __restrict__ QKV,
                                                   _Float16* __restrict__ Oh) {
  int hw = blockIdx.x;
  int lin = (hw & 7) * 128 + (hw >> 3);   // XCD-chunked
  int bh = lin >> 3, qt = lin & 7;
  int b = bh >> 3, h = bh & 7;
  int t = threadIdx.x, w = t >> 6, l = t & 63;
  int lg = l >> 4, lr = l & 15;

  __shared__ _Float16 Ks[2][64 * 128];    // [kv][16 segs of 8] seg XOR-swizzled by kv&7
  __shared__ _Float16 Vts[2][96 * 64];    // [d][kv], kv XOR-swizzled by ((d^(d>>3))&7)<<3
  __shared__ _Float16 Ps[8][16 * 64];     // per-wave [q][kv], kv XOR-swizzled by (q&7)<<3

  const _Float16* Qb = QKV + (size_t)b * 1024 * 2304 + h * 96;
  const _Float16* Kb = Qb + 768;
  const _Float16* Vb = Qb + 1536;

  half8 qf[3];
  {
    int qrow = qt * 128 + w * 16 + lr;
    const _Float16 s = (_Float16)1.4426950408889634f;  // LOG2E folded into Q
#pragma unroll
    for (int c = 0; c < 3; ++c) {
      qf[c] = *(const half8*)&Qb[(size_t)qrow * 2304 + c * 32 + lg * 8];
#pragma unroll
      for (int e = 0; e < 8; ++e) qf[c][e] = qf[c][e] * s;
    }
  }

  // ---- hoisted staging address math (tile-invariant) ----
  int ksrc[2], kdst[2];
#pragma unroll
  for (int j = 0; j < 2; ++j) {
    int slot = j * 512 + t;
    int kv = slot >> 4, seg = slot & 15;
    ksrc[j] = kv * 2304 + (seg ^ (kv & 7)) * 8;
    kdst[j] = slot * 8;
  }
  bool vact = t < 384;
  int kvp = t / 12, m = t % 12;
  int vsrc = 2 * kvp * 2304 + m * 8;
  int vdst[8];
#pragma unroll
  for (int e = 0; e < 8; ++e) {
    int d = m * 8 + e;
    int sw = ((d & 7) ^ ((d >> 3) & 7)) << 3;
    vdst[e] = d * 64 + ((2 * kvp) ^ sw);
  }
  int swq = (lr & 7) << 3;
  int poff[4];
#pragma unroll
  for (int tt = 0; tt < 4; ++tt) poff[tt] = lr * 64 + ((tt * 16 + lg * 4) ^ swq);

  auto stage = [&](int kv0, int bi) {
    size_t goff = (size_t)kv0 * 2304;
#pragma unroll
    for (int j = 0; j < 2; ++j)
      gload_lds16(Kb + goff + ksrc[j], &Ks[bi][kdst[j]]);
    if (vact) {
      const _Float16* vp = Vb + goff + vsrc;
      half8 v0 = *(const half8*)vp;
      half8 v1 = *(const half8*)(vp + 2304);
#pragma unroll
      for (int e = 0; e < 8; ++e) {
        union { _Float16 h2[2]; unsigned u32; } pk;
        pk.h2[0] = v0[e]; pk.h2[1] = v1[e];
        *(unsigned*)&Vts[bi][vdst[e]] = pk.u32;
      }
    }
  };

  float m_run = -3.0e38f, l_run = 0.f;
  f32x4 o_acc[6] = {};  // O[q=4g+i][d=cc*16+lr]

  stage(0, 0);

  for (int tile = 0; tile < 16; ++tile) {
    int bi = tile & 1;
    __syncthreads();  // drains vmcnt+lgkmcnt: stage(tile) ready, compute(tile-1) done
    if (tile + 1 < 16) stage((tile + 1) * 64, bi ^ 1);

    // --- S^T tiles: mfma(A=K[16kv][32d], B=Q^T) -> D[kv=4g+i][q=lr]
    f32x4 s_acc[4];
#pragma unroll
    for (int tt = 0; tt < 4; ++tt) {
      s_acc[tt] = f32x4{0.f, 0.f, 0.f, 0.f};
      int kvr = tt * 16 + lr;
#pragma unroll
      for (int c = 0; c < 3; ++c) {
        half8 kf = *(const half8*)&Ks[bi][kvr * 128 + ((c * 4 + lg) ^ (kvr & 7)) * 8];
        s_acc[tt] = __builtin_amdgcn_mfma_f32_16x16x32_f16(kf, qf[c], s_acc[tt], 0, 0, 0);
      }
    }

    // --- online softmax (log2 domain); lane owns q = lr
    float tmax = -3.0e38f;
#pragma unroll
    for (int tt = 0; tt < 4; ++tt)
#pragma unroll
      for (int i = 0; i < 4; ++i) tmax = fmaxf(tmax, s_acc[tt][i]);
    tmax = fmaxf(tmax, __shfl_xor(tmax, 16, 64));
    tmax = fmaxf(tmax, __shfl_xor(tmax, 32, 64));

    if (!__all(tmax <= m_run + 11.5f)) {   // defer-max: rescale only on real growth
      float m_new = fmaxf(m_run, tmax);
      float scale = __builtin_exp2f(m_run - m_new);
      float sc0 = __shfl(scale, lg * 4 + 0, 64);
      float sc1 = __shfl(scale, lg * 4 + 1, 64);
      float sc2 = __shfl(scale, lg * 4 + 2, 64);
      float sc3 = __shfl(scale, lg * 4 + 3, 64);
#pragma unroll
      for (int cc = 0; cc < 6; ++cc) {
        o_acc[cc][0] *= sc0; o_acc[cc][1] *= sc1;
        o_acc[cc][2] *= sc2; o_acc[cc][3] *= sc3;
      }
      l_run *= scale;
      m_run = m_new;
    }

    float rs = 0.f;
#pragma unroll
    for (int tt = 0; tt < 4; ++tt) {
      float p0 = __builtin_exp2f(s_acc[tt][0] - m_run);
      float p1 = __builtin_exp2f(s_acc[tt][1] - m_run);
      float p2 = __builtin_exp2f(s_acc[tt][2] - m_run);
      float p3 = __builtin_exp2f(s_acc[tt][3] - m_run);
      rs += (p0 + p1) + (p2 + p3);
      union { fp16x2 h2[2]; unsigned long long u64; } pk;
      pk.h2[0] = __builtin_amdgcn_cvt_pkrtz(p0, p1);
      pk.h2[1] = __builtin_amdgcn_cvt_pkrtz(p2, p3);
      *(unsigned long long*)&Ps[w][poff[tt]] = pk.u64;  // wave-private, no barrier
    }
    rs += __shfl_xor(rs, 16, 64);
    rs += __shfl_xor(rs, 32, 64);
    l_run += rs;

    // --- PV: O += P[16q][32kv] * V[32kv][16d] per (kc, cc)
#pragma unroll
    for (int kc = 0; kc < 2; ++kc) {
      half8 pf = *(const half8*)&Ps[w][lr * 64 + ((kc * 32 + lg * 8) ^ swq)];
#pragma unroll
      for (int cc = 0; cc < 6; ++cc) {
        int d = cc * 16 + lr;
        int sw = ((d & 7) ^ ((d >> 3) & 7)) << 3;
        half8 vf = *(const half8*)&Vts[bi][d * 64 + ((kc * 32 + lg * 8) ^ sw)];
        o_acc[cc] = __builtin_amdgcn_mfma_f32_16x16x32_f16(pf, vf, o_acc[cc], 0, 0, 0);
      }
    }
  }

  // --- epilogue: O /= (l_run * sqrt(768)) — the reference's post-softmax scaling
  float inv = 1.0f / (l_run * 27.712812921102035f);
  float iv0 = __shfl(inv, lg * 4 + 0, 64);
  float iv1 = __shfl(inv, lg * 4 + 1, 64);
  float iv2 = __shfl(inv, lg * 4 + 2, 64);
  float iv3 = __shfl(inv, lg * 4 + 3, 64);
  size_t rbase = (size_t)(b * 1024 + qt * 128 + w * 16) * 768 + h * 96;
#pragma unroll
  for (int cc = 0; cc < 6; ++cc) {
    int col = cc * 16 + lr;
    Oh[rbase + (size_t)(lg * 4 + 0) * 768 + col] = (_Float16)(o_acc[cc][0] * iv0);
    Oh[rbase + (size_t)(lg * 4 + 1) * 768 + col] = (_Float16)(o_acc[cc][1] * iv1);
    Oh[rbase + (size_t)(lg * 4 + 2) * 768 + col] = (_Float16)(o_acc[cc][2] * iv2);
    Oh[rbase + (size_t)(lg * 4 + 3) * 768 + col] = (_Float16)(o_acc[cc][3] * iv3);
  }
}

// ---------------- launch ----------------

extern "C" void kernel_launch(void* const* d_in, const int* in_sizes, int n_in,
                              void* d_out, int out_size, void* d_ws, size_t ws_size,
                              hipStream_t stream) {
  const float* x  = (const float*)d_in[0];
  const float* Wq = (const float*)d_in[1];
  const float* bq = (const float*)d_in[2];
  const float* Wk = (const float*)d_in[3];
  const float* bk = (const float*)d_in[4];
  const float* Wv = (const float*)d_in[5];
  const float* bv = (const float*)d_in[6];
  const float* Wo = (const float*)d_in[7];
  const float* bo = (const float*)d_in[8];
  float* out = (float*)d_out;

  char* ws = (char*)d_ws;
  _Float16* WT   = (_Float16*)(ws);                // 4,718,592 B
  float*    bias = (float*)(ws + 4718592);         // 9,216 B (padded to 32K)
  _Float16* xh   = (_Float16*)(ws + 4751360);      // 25,165,824 B
  _Float16* QKV  = (_Float16*)(ws + 29917184);     // 75,497,472 B
  _Float16* Oh   = (_Float16*)(ws + 105414656);    // 25,165,824 B  (total ~130.6 MB)

  conv_x_kernel<<<6144, 256, 0, stream>>>(x, xh);
  transpose_cvt_kernel<<<dim3(24, 24, 4), dim3(32, 8), 0, stream>>>(Wq, Wk, Wv, Wo, WT);
  conv_bias_kernel<<<9, 256, 0, stream>>>(bq, bk, bv, bias);

  // QKV: M=16384, N=2304, K=768 -> grid 128*18 = 2304 (div by 8 for XCD swizzle)
  gemm_nt_kernel<1><<<2304, 256, 0, stream>>>(xh, WT, bias, QKV, 16384, 2304, 768, 2304);

  attn_kernel<<<1024, 512, 0, stream>>>(QKV, Oh);

  // out-proj: M=16384, N=768, K=768 -> grid 128*6 = 768
  gemm_nt_kernel<0><<<768, 256, 0, stream>>>(Oh, WT + (size_t)2304 * 768, bo, out,
                                             16384, 768, 768, 768);
}